// Round 3
// baseline (6312.883 us; speedup 1.0000x reference)
//
#include <hip/hip_runtime.h>
#include <hip/hip_bf16.h>
#include <math.h>

constexpr int kD  = 1024;
constexpr int kP  = 512;
constexpr int kH  = 16;
constexpr int kFF = 4096;
constexpr int kHD = 64;
constexpr int kB  = 2;
constexpr int kL  = 1024;
constexpr int kTok = kB * kL;   // 2048

// ---------------- GEMM: C[M,N] = A[M,K] @ W[K,N] + bias, opt exact GELU; all fp32 ----------------
// M%64==0, N%64==0, K%16==0 (always true here)
__global__ __launch_bounds__(256) void gemm_bias(
    const float* __restrict__ A, const float* __restrict__ W,
    const float* __restrict__ bias, float* __restrict__ C,
    int M, int N, int K, int act)
{
    __shared__ float As[16][65];
    __shared__ float Ws[16][65];
    const int tid = threadIdx.x;
    const int tx = tid & 15, ty = tid >> 4;
    const int m0 = blockIdx.y * 64, n0 = blockIdx.x * 64;
    float acc[4][4] = {};
    for (int kk = 0; kk < K; kk += 16) {
        #pragma unroll
        for (int e = 0; e < 4; ++e) {
            int idx = tid * 4 + e;          // 0..1023
            int m = idx >> 4;               // 0..63
            int kx = idx & 15;
            As[kx][m] = A[(size_t)(m0 + m) * K + kk + kx];
        }
        #pragma unroll
        for (int e = 0; e < 4; ++e) {
            int idx = tid + e * 256;
            int kx = idx >> 6;              // 0..15
            int n = idx & 63;
            Ws[kx][n] = W[(size_t)(kk + kx) * N + n0 + n];
        }
        __syncthreads();
        #pragma unroll
        for (int kx = 0; kx < 16; ++kx) {
            float a[4], bb[4];
            #pragma unroll
            for (int i = 0; i < 4; ++i) a[i] = As[kx][ty * 4 + i];
            #pragma unroll
            for (int j = 0; j < 4; ++j) bb[j] = Ws[kx][tx * 4 + j];
            #pragma unroll
            for (int i = 0; i < 4; ++i)
                #pragma unroll
                for (int j = 0; j < 4; ++j)
                    acc[i][j] += a[i] * bb[j];
        }
        __syncthreads();
    }
    #pragma unroll
    for (int i = 0; i < 4; ++i) {
        int m = m0 + ty * 4 + i;
        #pragma unroll
        for (int j = 0; j < 4; ++j) {
            int n = n0 + tx * 4 + j;
            float vv = acc[i][j] + bias[n];
            if (act == 1) vv = vv * 0.5f * (1.0f + erff(vv * 0.70710678118654752f));
            C[(size_t)m * N + n] = vv;
        }
    }
}

// ---------------- RoPE in-place: x [Tok, D] viewed as [Tok, H, 64], pos [L, 64] angles ----------------
__global__ void rope_kernel(float* __restrict__ x, const float* __restrict__ pos) {
    int idx = blockIdx.x * blockDim.x + threadIdx.x;   // over Tok*H*32 = 1M
    if (idx >= kTok * kH * 32) return;
    int d = idx & 31;
    int h = (idx >> 5) & (kH - 1);
    int row = idx >> 9;
    int l = row & (kL - 1);
    float a1 = pos[l * kHD + d];
    float a2 = pos[l * kHD + d + 32];
    size_t base = (size_t)row * kD + h * kHD;
    float x1 = x[base + d], x2 = x[base + d + 32];
    // out[d]    = x1*cos(a1) - x2*sin(a1)   (rotate_half: first half gets -x2)
    // out[d+32] = x2*cos(a2) + x1*sin(a2)
    x[base + d]      = x1 * cosf(a1) - x2 * sinf(a1);
    x[base + d + 32] = x2 * cosf(a2) + x1 * sinf(a2);
}

// ---------------- attention: one block per (b,h,qi); q/k/v [Tok, D] head-sliced ----------------
__global__ __launch_bounds__(256) void attn_kernel(
    const float* __restrict__ q, const float* __restrict__ k,
    const float* __restrict__ v, const float* __restrict__ alibi,
    const int* __restrict__ mask, float* __restrict__ out)
{
    const int qi = blockIdx.x, h = blockIdx.y, b = blockIdx.z;
    const int tid = threadIdx.x;
    __shared__ float sc[kL];
    __shared__ float qrow[kHD];
    __shared__ float red[256];
    if (tid < kHD) qrow[tid] = q[(size_t)(b * kL + qi) * kD + h * kHD + tid];
    __syncthreads();
    // scores (mask -> -1e30 before +alibi, matching reference order)
    for (int kk = tid; kk < kL; kk += 256) {
        const float* krow = k + (size_t)(b * kL + kk) * kD + h * kHD;
        float dot = 0.f;
        #pragma unroll
        for (int d = 0; d < kHD; ++d) dot += qrow[d] * krow[d];
        float s = mask[b * kL + kk] ? -1e30f : dot * 0.125f;  // HD^-0.5 = 1/8
        s += alibi[((size_t)h * kL + qi) * kL + kk];
        sc[kk] = s;
    }
    __syncthreads();
    // max reduce
    float lm = -1e30f;
    for (int kk = tid; kk < kL; kk += 256) lm = fmaxf(lm, sc[kk]);
    red[tid] = lm; __syncthreads();
    for (int s = 128; s > 0; s >>= 1) {
        if (tid < s) red[tid] = fmaxf(red[tid], red[tid + s]);
        __syncthreads();
    }
    float m = red[0];
    __syncthreads();
    // exp + sum
    float ls = 0.f;
    for (int kk = tid; kk < kL; kk += 256) { float e = expf(sc[kk] - m); sc[kk] = e; ls += e; }
    red[tid] = ls; __syncthreads();
    for (int s = 128; s > 0; s >>= 1) {
        if (tid < s) red[tid] += red[tid + s];
        __syncthreads();
    }
    float inv = 1.f / red[0];
    __syncthreads();
    // P @ V : 4 chunks of 256 keys, 64 dims
    int pd = tid & 63, chunk = tid >> 6;
    float acc = 0.f;
    int k0 = chunk * 256;
    for (int kk = k0; kk < k0 + 256; ++kk)
        acc += sc[kk] * v[(size_t)(b * kL + kk) * kD + h * kHD + pd];
    red[tid] = acc; __syncthreads();
    if (tid < 64)
        out[(size_t)(b * kL + qi) * kD + h * kHD + tid] =
            (red[tid] + red[tid + 64] + red[tid + 128] + red[tid + 192]) * inv;
}

// ---------------- out = res + LayerNorm(z) ----------------
__global__ __launch_bounds__(256) void add_ln(
    const float* __restrict__ res, const float* __restrict__ z,
    const float* __restrict__ g, const float* __restrict__ bi,
    float* __restrict__ out)
{
    int row = blockIdx.x, tid = threadIdx.x;
    __shared__ float red[256], red2[256];
    const float* zr = z + (size_t)row * kD;
    float s = 0.f, sq = 0.f;
    for (int i = tid; i < kD; i += 256) { float vv = zr[i]; s += vv; sq += vv * vv; }
    red[tid] = s; red2[tid] = sq; __syncthreads();
    for (int st = 128; st > 0; st >>= 1) {
        if (tid < st) { red[tid] += red[tid + st]; red2[tid] += red2[tid + st]; }
        __syncthreads();
    }
    float mean = red[0] / kD;
    float var = red2[0] / kD - mean * mean;
    float rstd = rsqrtf(var + 1e-5f);
    for (int i = tid; i < kD; i += 256) {
        float vv = (zr[i] - mean) * rstd * g[i] + bi[i];
        out[(size_t)row * kD + i] = res[(size_t)row * kD + i] + vv;
    }
}

// ---------------- out = LayerNorm(res + f) ----------------
__global__ __launch_bounds__(256) void ln_final(
    const float* __restrict__ res, const float* __restrict__ f,
    const float* __restrict__ g, const float* __restrict__ bi,
    float* __restrict__ out)
{
    int row = blockIdx.x, tid = threadIdx.x;
    __shared__ float tt[kD];
    __shared__ float red[256], red2[256];
    float s = 0.f, sq = 0.f;
    for (int i = tid; i < kD; i += 256) {
        float vv = res[(size_t)row * kD + i] + f[(size_t)row * kD + i];
        tt[i] = vv; s += vv; sq += vv * vv;
    }
    red[tid] = s; red2[tid] = sq; __syncthreads();
    for (int st = 128; st > 0; st >>= 1) {
        if (tid < st) { red[tid] += red[tid + st]; red2[tid] += red2[tid + st]; }
        __syncthreads();
    }
    float mean = red[0] / kD;
    float var = red2[0] / kD - mean * mean;
    float rstd = rsqrtf(var + 1e-5f);
    for (int i = tid; i < kD; i += 256)
        out[(size_t)row * kD + i] = (tt[i] - mean) * rstd * g[i] + bi[i];
}

extern "C" void kernel_launch(void* const* d_in, const int* in_sizes, int n_in,
                              void* d_out, int out_size, void* d_ws, size_t ws_size,
                              hipStream_t stream)
{
    const float* memory      = (const float*)d_in[0];
    const float* tgt         = (const float*)d_in[1];
    const float* self_alibi  = (const float*)d_in[2];
    const float* self_pos    = (const float*)d_in[3];
    const float* cross_alibi = (const float*)d_in[4];
    const float* cross_pos   = (const float*)d_in[5];
    const int*   mask        = (const int*)d_in[6];
    const float* sa_lat_w = (const float*)d_in[7];   const float* sa_lat_b = (const float*)d_in[8];
    const float* sa_q_w   = (const float*)d_in[9];   const float* sa_q_b   = (const float*)d_in[10];
    const float* sa_k_w   = (const float*)d_in[11];  const float* sa_k_b   = (const float*)d_in[12];
    const float* sa_v_w   = (const float*)d_in[13];  const float* sa_v_b   = (const float*)d_in[14];
    const float* sa_out_w = (const float*)d_in[15];  const float* sa_out_b = (const float*)d_in[16];
    const float* ca_lat_w = (const float*)d_in[17];  const float* ca_lat_b = (const float*)d_in[18];
    const float* ca_q_w   = (const float*)d_in[19];  const float* ca_q_b   = (const float*)d_in[20];
    const float* ca_k_w   = (const float*)d_in[21];  const float* ca_k_b   = (const float*)d_in[22];
    const float* ca_v_w   = (const float*)d_in[23];  const float* ca_v_b   = (const float*)d_in[24];
    const float* ca_out_w = (const float*)d_in[25];  const float* ca_out_b = (const float*)d_in[26];
    const float* lin1_w   = (const float*)d_in[27];  const float* lin1_b   = (const float*)d_in[28];
    const float* lin2_w   = (const float*)d_in[29];  const float* lin2_b   = (const float*)d_in[30];
    const float* n1_g = (const float*)d_in[31];  const float* n1_b = (const float*)d_in[32];
    const float* n2_g = (const float*)d_in[33];  const float* n2_b = (const float*)d_in[34];
    const float* n3_g = (const float*)d_in[35];  const float* n3_b = (const float*)d_in[36];

    // workspace layout (fp32), 13M floats = 52 MB total
    const size_t M1 = 1u << 20;
    float* W    = (float*)d_ws;
    float* xb   = W + 0 * M1;    // 2M — residual stream
    float* tmp  = W + 2 * M1;    // 2M — pre-LN tensor
    float* proj = W + 4 * M1;    // 1M — latent projection
    float* qb   = W + 5 * M1;    // 2M
    float* kb   = W + 7 * M1;    // 2M
    float* vb   = W + 9 * M1;    // 2M
    float* attn = W + 11 * M1;   // 2M
    float* ffh  = W + 4 * M1;    // 8M — overlays proj/q/k/v/attn during FFN

    auto gemm = [&](const float* A, const float* Wt, const float* bias, float* C,
                    int M, int N, int K, int act) {
        gemm_bias<<<dim3(N / 64, M / 64), dim3(256), 0, stream>>>(A, Wt, bias, C, M, N, K, act);
    };

    // ---- self attention ----
    gemm(tgt, sa_lat_w, sa_lat_b, proj, kTok, kP, kD, 0);
    gemm(proj, sa_q_w, sa_q_b, qb, kTok, kD, kP, 0);
    gemm(proj, sa_k_w, sa_k_b, kb, kTok, kD, kP, 0);
    gemm(proj, sa_v_w, sa_v_b, vb, kTok, kD, kP, 0);
    rope_kernel<<<dim3(4096), dim3(256), 0, stream>>>(qb, self_pos);
    rope_kernel<<<dim3(4096), dim3(256), 0, stream>>>(kb, self_pos);
    attn_kernel<<<dim3(kL, kH, kB), dim3(256), 0, stream>>>(qb, kb, vb, self_alibi, mask, attn);
    gemm(attn, sa_out_w, sa_out_b, tmp, kTok, kD, kD, 0);
    add_ln<<<dim3(kTok), dim3(256), 0, stream>>>(tgt, tmp, n1_g, n1_b, xb);

    // ---- cross attention ----
    gemm(memory, ca_lat_w, ca_lat_b, proj, kTok, kP, kD, 0);
    gemm(xb, ca_q_w, ca_q_b, qb, kTok, kD, kD, 0);
    gemm(proj, ca_k_w, ca_k_b, kb, kTok, kD, kP, 0);
    gemm(proj, ca_v_w, ca_v_b, vb, kTok, kD, kP, 0);
    rope_kernel<<<dim3(4096), dim3(256), 0, stream>>>(qb, cross_pos);
    rope_kernel<<<dim3(4096), dim3(256), 0, stream>>>(kb, cross_pos);
    attn_kernel<<<dim3(kL, kH, kB), dim3(256), 0, stream>>>(qb, kb, vb, cross_alibi, mask, attn);
    gemm(attn, ca_out_w, ca_out_b, tmp, kTok, kD, kD, 0);
    add_ln<<<dim3(kTok), dim3(256), 0, stream>>>(xb, tmp, n2_g, n2_b, xb);

    // ---- FFN ----
    gemm(xb, lin1_w, lin1_b, ffh, kTok, kFF, kD, 1);
    gemm(ffh, lin2_w, lin2_b, tmp, kTok, kD, kFF, 0);
    ln_final<<<dim3(kTok), dim3(256), 0, stream>>>(xb, tmp, n3_g, n3_b, (float*)d_out);
}

// Round 4
// 2133.902 us; speedup vs baseline: 2.9584x; 2.9584x over previous
//
#include <hip/hip_runtime.h>
#include <hip/hip_bf16.h>
#include <math.h>

constexpr int kD  = 1024;
constexpr int kP  = 512;
constexpr int kH  = 16;
constexpr int kFF = 4096;
constexpr int kHD = 64;
constexpr int kB  = 2;
constexpr int kL  = 1024;
constexpr int kTok = kB * kL;   // 2048

// ---------------- GEMM: C[M,N] = A[M,K] @ W[K,N] + bias, opt exact GELU; all fp32 ----------------
__global__ __launch_bounds__(256) void gemm_bias(
    const float* __restrict__ A, const float* __restrict__ W,
    const float* __restrict__ bias, float* __restrict__ C,
    int M, int N, int K, int act)
{
    __shared__ float As[16][65];
    __shared__ float Ws[16][65];
    const int tid = threadIdx.x;
    const int tx = tid & 15, ty = tid >> 4;
    const int m0 = blockIdx.y * 64, n0 = blockIdx.x * 64;
    float acc[4][4] = {};
    for (int kk = 0; kk < K; kk += 16) {
        #pragma unroll
        for (int e = 0; e < 4; ++e) {
            int idx = tid * 4 + e;
            int m = idx >> 4;
            int kx = idx & 15;
            As[kx][m] = A[(size_t)(m0 + m) * K + kk + kx];
        }
        #pragma unroll
        for (int e = 0; e < 4; ++e) {
            int idx = tid + e * 256;
            int kx = idx >> 6;
            int n = idx & 63;
            Ws[kx][n] = W[(size_t)(kk + kx) * N + n0 + n];
        }
        __syncthreads();
        #pragma unroll
        for (int kx = 0; kx < 16; ++kx) {
            float a[4], bb[4];
            #pragma unroll
            for (int i = 0; i < 4; ++i) a[i] = As[kx][ty * 4 + i];
            #pragma unroll
            for (int j = 0; j < 4; ++j) bb[j] = Ws[kx][tx * 4 + j];
            #pragma unroll
            for (int i = 0; i < 4; ++i)
                #pragma unroll
                for (int j = 0; j < 4; ++j)
                    acc[i][j] += a[i] * bb[j];
        }
        __syncthreads();
    }
    #pragma unroll
    for (int i = 0; i < 4; ++i) {
        int m = m0 + ty * 4 + i;
        #pragma unroll
        for (int j = 0; j < 4; ++j) {
            int n = n0 + tx * 4 + j;
            float vv = acc[i][j] + bias[n];
            if (act == 1) vv = vv * 0.5f * (1.0f + erff(vv * 0.70710678118654752f));
            C[(size_t)m * N + n] = vv;
        }
    }
}

// ---------------- RoPE in-place ----------------
__global__ void rope_kernel(float* __restrict__ x, const float* __restrict__ pos) {
    int idx = blockIdx.x * blockDim.x + threadIdx.x;
    if (idx >= kTok * kH * 32) return;
    int d = idx & 31;
    int h = (idx >> 5) & (kH - 1);
    int row = idx >> 9;
    int l = row & (kL - 1);
    float a1 = pos[l * kHD + d];
    float a2 = pos[l * kHD + d + 32];
    size_t base = (size_t)row * kD + h * kHD;
    float x1 = x[base + d], x2 = x[base + d + 32];
    x[base + d]      = x1 * cosf(a1) - x2 * sinf(a1);
    x[base + d + 32] = x2 * cosf(a2) + x1 * sinf(a2);
}

// ---------------- flash-style tiled attention ----------------
// one block per (b, h, 64-q-row tile); online softmax; 4x4 register blocking.
// LDS: QsT/KsT transposed [HD][64+4] so QK^T is an outer product (2 x b128 -> 16 FMA);
// SsT [key][q] so softmax row-scan is bank-conflict-free and PV is an outer product.
constexpr int TQ = 64, TK = 64;
constexpr int LDP = 68;   // padded leading dim: 68*4 = 272 B, 16B-aligned; hot reads 2-way aliased (free)
__global__ __launch_bounds__(256) void attn_tile(
    const float* __restrict__ q, const float* __restrict__ k,
    const float* __restrict__ v, const float* __restrict__ alibi,
    const int* __restrict__ mask, float* __restrict__ out)
{
    const int q0 = blockIdx.x * TQ, h = blockIdx.y, b = blockIdx.z;
    const int tid = threadIdx.x;
    const int tx = tid & 15, ty = tid >> 4;
    __shared__ float QsT[kHD][LDP];  // [kd][q]
    __shared__ float KsT[kHD][LDP];  // [kd][key]
    __shared__ float Vs[TK][LDP];    // [key][c]
    __shared__ float SsT[TK][LDP];   // [key][q]  (scores, then P)
    __shared__ float mrow[TQ], lrow[TQ], arow[TQ];

    // load Q tile (transposed into LDS)
    #pragma unroll
    for (int e = 0; e < 4; ++e) {
        int i = tid + e * 256;            // 0..1023
        int r = i >> 4, c4 = (i & 15) * 4;
        const float4 qv = *(const float4*)&q[(size_t)(b * kL + q0 + r) * kD + h * kHD + c4];
        QsT[c4][r] = qv.x; QsT[c4 + 1][r] = qv.y; QsT[c4 + 2][r] = qv.z; QsT[c4 + 3][r] = qv.w;
    }
    if (tid < TQ) { mrow[tid] = -3e38f; lrow[tid] = 0.f; }
    float o[4][4] = {};
    __syncthreads();

    for (int k0 = 0; k0 < kL; k0 += TK) {
        // ---- load K (transposed) and V (row-major) tiles, coalesced float4 ----
        #pragma unroll
        for (int e = 0; e < 4; ++e) {
            int i = tid + e * 256;
            int r = i >> 4, c4 = (i & 15) * 4;
            size_t g = (size_t)(b * kL + k0 + r) * kD + h * kHD + c4;
            const float4 kv = *(const float4*)&k[g];
            KsT[c4][r] = kv.x; KsT[c4 + 1][r] = kv.y; KsT[c4 + 2][r] = kv.z; KsT[c4 + 3][r] = kv.w;
            const float4 vv = *(const float4*)&v[g];
            Vs[r][c4] = vv.x; Vs[r][c4 + 1] = vv.y; Vs[r][c4 + 2] = vv.z; Vs[r][c4 + 3] = vv.w;
        }
        __syncthreads();

        // ---- S = Q K^T, 4x4 outer-product blocking ----
        float acc[4][4] = {};
        #pragma unroll 8
        for (int kd = 0; kd < kHD; ++kd) {
            float4 a4 = *(const float4*)&QsT[kd][ty * 4];
            float4 b4 = *(const float4*)&KsT[kd][tx * 4];
            const float av[4] = {a4.x, a4.y, a4.z, a4.w};
            const float bv[4] = {b4.x, b4.y, b4.z, b4.w};
            #pragma unroll
            for (int i = 0; i < 4; ++i)
                #pragma unroll
                for (int j = 0; j < 4; ++j)
                    acc[i][j] += av[i] * bv[j];
        }
        // scale + mask + alibi, store transposed [key][q]
        const int4 mk = *(const int4*)&mask[b * kL + k0 + tx * 4];
        const int mkv[4] = {mk.x, mk.y, mk.z, mk.w};
        #pragma unroll
        for (int i = 0; i < 4; ++i) {
            const float4 al = *(const float4*)&alibi[((size_t)h * kL + q0 + ty * 4 + i) * kL + k0 + tx * 4];
            const float alv[4] = {al.x, al.y, al.z, al.w};
            #pragma unroll
            for (int j = 0; j < 4; ++j) {
                float s = mkv[j] ? -1e30f : acc[i][j] * 0.125f;
                SsT[tx * 4 + j][ty * 4 + i] = s + alv[j];
            }
        }
        __syncthreads();

        // ---- online softmax per q-row (thread r owns row r) ----
        if (tid < TQ) {
            float tm = -3e38f;
            #pragma unroll 8
            for (int kk = 0; kk < TK; ++kk) tm = fmaxf(tm, SsT[kk][tid]);
            float mo = mrow[tid];
            float mn = fmaxf(mo, tm);
            float al = __expf(mo - mn);
            float ls = 0.f;
            #pragma unroll 8
            for (int kk = 0; kk < TK; ++kk) {
                float p = __expf(SsT[kk][tid] - mn);
                SsT[kk][tid] = p;
                ls += p;
            }
            mrow[tid] = mn;
            lrow[tid] = lrow[tid] * al + ls;
            arow[tid] = al;
        }
        __syncthreads();

        // ---- O = O*alpha + P V, outer-product blocking ----
        float alf[4];
        #pragma unroll
        for (int i = 0; i < 4; ++i) alf[i] = arow[ty * 4 + i];
        #pragma unroll
        for (int i = 0; i < 4; ++i)
            #pragma unroll
            for (int j = 0; j < 4; ++j)
                o[i][j] *= alf[i];
        #pragma unroll 8
        for (int kk = 0; kk < TK; ++kk) {
            float4 p4 = *(const float4*)&SsT[kk][ty * 4];
            float4 v4 = *(const float4*)&Vs[kk][tx * 4];
            const float pv[4] = {p4.x, p4.y, p4.z, p4.w};
            const float vv[4] = {v4.x, v4.y, v4.z, v4.w};
            #pragma unroll
            for (int i = 0; i < 4; ++i)
                #pragma unroll
                for (int j = 0; j < 4; ++j)
                    o[i][j] += pv[i] * vv[j];
        }
        __syncthreads();
    }

    // ---- epilogue: divide by l, coalesced float4 stores ----
    #pragma unroll
    for (int i = 0; i < 4; ++i) {
        float inv = 1.f / lrow[ty * 4 + i];
        float4 ov = make_float4(o[i][0] * inv, o[i][1] * inv, o[i][2] * inv, o[i][3] * inv);
        *(float4*)&out[(size_t)(b * kL + q0 + ty * 4 + i) * kD + h * kHD + tx * 4] = ov;
    }
}

// ---------------- out = res + LayerNorm(z) ----------------
__global__ __launch_bounds__(256) void add_ln(
    const float* __restrict__ res, const float* __restrict__ z,
    const float* __restrict__ g, const float* __restrict__ bi,
    float* __restrict__ out)
{
    int row = blockIdx.x, tid = threadIdx.x;
    __shared__ float red[256], red2[256];
    const float* zr = z + (size_t)row * kD;
    float s = 0.f, sq = 0.f;
    for (int i = tid; i < kD; i += 256) { float vv = zr[i]; s += vv; sq += vv * vv; }
    red[tid] = s; red2[tid] = sq; __syncthreads();
    for (int st = 128; st > 0; st >>= 1) {
        if (tid < st) { red[tid] += red[tid + st]; red2[tid] += red2[tid + st]; }
        __syncthreads();
    }
    float mean = red[0] / kD;
    float var = red2[0] / kD - mean * mean;
    float rstd = rsqrtf(var + 1e-5f);
    for (int i = tid; i < kD; i += 256) {
        float vv = (zr[i] - mean) * rstd * g[i] + bi[i];
        out[(size_t)row * kD + i] = res[(size_t)row * kD + i] + vv;
    }
}

// ---------------- out = LayerNorm(res + f) ----------------
__global__ __launch_bounds__(256) void ln_final(
    const float* __restrict__ res, const float* __restrict__ f,
    const float* __restrict__ g, const float* __restrict__ bi,
    float* __restrict__ out)
{
    int row = blockIdx.x, tid = threadIdx.x;
    __shared__ float tt[kD];
    __shared__ float red[256], red2[256];
    float s = 0.f, sq = 0.f;
    for (int i = tid; i < kD; i += 256) {
        float vv = res[(size_t)row * kD + i] + f[(size_t)row * kD + i];
        tt[i] = vv; s += vv; sq += vv * vv;
    }
    red[tid] = s; red2[tid] = sq; __syncthreads();
    for (int st = 128; st > 0; st >>= 1) {
        if (tid < st) { red[tid] += red[tid + st]; red2[tid] += red2[tid + st]; }
        __syncthreads();
    }
    float mean = red[0] / kD;
    float var = red2[0] / kD - mean * mean;
    float rstd = rsqrtf(var + 1e-5f);
    for (int i = tid; i < kD; i += 256)
        out[(size_t)row * kD + i] = (tt[i] - mean) * rstd * g[i] + bi[i];
}

extern "C" void kernel_launch(void* const* d_in, const int* in_sizes, int n_in,
                              void* d_out, int out_size, void* d_ws, size_t ws_size,
                              hipStream_t stream)
{
    const float* memory      = (const float*)d_in[0];
    const float* tgt         = (const float*)d_in[1];
    const float* self_alibi  = (const float*)d_in[2];
    const float* self_pos    = (const float*)d_in[3];
    const float* cross_alibi = (const float*)d_in[4];
    const float* cross_pos   = (const float*)d_in[5];
    const int*   mask        = (const int*)d_in[6];
    const float* sa_lat_w = (const float*)d_in[7];   const float* sa_lat_b = (const float*)d_in[8];
    const float* sa_q_w   = (const float*)d_in[9];   const float* sa_q_b   = (const float*)d_in[10];
    const float* sa_k_w   = (const float*)d_in[11];  const float* sa_k_b   = (const float*)d_in[12];
    const float* sa_v_w   = (const float*)d_in[13];  const float* sa_v_b   = (const float*)d_in[14];
    const float* sa_out_w = (const float*)d_in[15];  const float* sa_out_b = (const float*)d_in[16];
    const float* ca_lat_w = (const float*)d_in[17];  const float* ca_lat_b = (const float*)d_in[18];
    const float* ca_q_w   = (const float*)d_in[19];  const float* ca_q_b   = (const float*)d_in[20];
    const float* ca_k_w   = (const float*)d_in[21];  const float* ca_k_b   = (const float*)d_in[22];
    const float* ca_v_w   = (const float*)d_in[23];  const float* ca_v_b   = (const float*)d_in[24];
    const float* ca_out_w = (const float*)d_in[25];  const float* ca_out_b = (const float*)d_in[26];
    const float* lin1_w   = (const float*)d_in[27];  const float* lin1_b   = (const float*)d_in[28];
    const float* lin2_w   = (const float*)d_in[29];  const float* lin2_b   = (const float*)d_in[30];
    const float* n1_g = (const float*)d_in[31];  const float* n1_b = (const float*)d_in[32];
    const float* n2_g = (const float*)d_in[33];  const float* n2_b = (const float*)d_in[34];
    const float* n3_g = (const float*)d_in[35];  const float* n3_b = (const float*)d_in[36];

    // workspace layout (fp32), 13M floats = 52 MB total
    const size_t M1 = 1u << 20;
    float* W    = (float*)d_ws;
    float* xb   = W + 0 * M1;    // 2M — residual stream
    float* tmp  = W + 2 * M1;    // 2M — pre-LN tensor
    float* proj = W + 4 * M1;    // 1M — latent projection
    float* qb   = W + 5 * M1;    // 2M
    float* kb   = W + 7 * M1;    // 2M
    float* vb   = W + 9 * M1;    // 2M
    float* attn = W + 11 * M1;   // 2M
    float* ffh  = W + 4 * M1;    // 8M — overlays proj/q/k/v/attn during FFN

    auto gemm = [&](const float* A, const float* Wt, const float* bias, float* C,
                    int M, int N, int K, int act) {
        gemm_bias<<<dim3(N / 64, M / 64), dim3(256), 0, stream>>>(A, Wt, bias, C, M, N, K, act);
    };
    dim3 agrid(kL / TQ, kH, kB);

    // ---- self attention ----
    gemm(tgt, sa_lat_w, sa_lat_b, proj, kTok, kP, kD, 0);
    gemm(proj, sa_q_w, sa_q_b, qb, kTok, kD, kP, 0);
    gemm(proj, sa_k_w, sa_k_b, kb, kTok, kD, kP, 0);
    gemm(proj, sa_v_w, sa_v_b, vb, kTok, kD, kP, 0);
    rope_kernel<<<dim3(4096), dim3(256), 0, stream>>>(qb, self_pos);
    rope_kernel<<<dim3(4096), dim3(256), 0, stream>>>(kb, self_pos);
    attn_tile<<<agrid, dim3(256), 0, stream>>>(qb, kb, vb, self_alibi, mask, attn);
    gemm(attn, sa_out_w, sa_out_b, tmp, kTok, kD, kD, 0);
    add_ln<<<dim3(kTok), dim3(256), 0, stream>>>(tgt, tmp, n1_g, n1_b, xb);

    // ---- cross attention ----
    gemm(memory, ca_lat_w, ca_lat_b, proj, kTok, kP, kD, 0);
    gemm(xb, ca_q_w, ca_q_b, qb, kTok, kD, kD, 0);
    gemm(proj, ca_k_w, ca_k_b, kb, kTok, kD, kP, 0);
    gemm(proj, ca_v_w, ca_v_b, vb, kTok, kD, kP, 0);
    rope_kernel<<<dim3(4096), dim3(256), 0, stream>>>(qb, cross_pos);
    rope_kernel<<<dim3(4096), dim3(256), 0, stream>>>(kb, cross_pos);
    attn_tile<<<agrid, dim3(256), 0, stream>>>(qb, kb, vb, cross_alibi, mask, attn);
    gemm(attn, ca_out_w, ca_out_b, tmp, kTok, kD, kD, 0);
    add_ln<<<dim3(kTok), dim3(256), 0, stream>>>(xb, tmp, n2_g, n2_b, xb);

    // ---- FFN ----
    gemm(xb, lin1_w, lin1_b, ffh, kTok, kFF, kD, 1);
    gemm(ffh, lin2_w, lin2_b, tmp, kTok, kD, kFF, 0);
    ln_final<<<dim3(kTok), dim3(256), 0, stream>>>(xb, tmp, n3_g, n3_b, (float*)d_out);
}

// Round 5
// 1151.119 us; speedup vs baseline: 5.4841x; 1.8538x over previous
//
#include <hip/hip_runtime.h>
#include <hip/hip_bf16.h>
#include <math.h>

typedef __hip_bfloat16 hbf16;
typedef __attribute__((ext_vector_type(8))) short bf16x8;
typedef __attribute__((ext_vector_type(4))) float f32x4;

constexpr int kD  = 1024;
constexpr int kP  = 512;
constexpr int kH  = 16;
constexpr int kFF = 4096;
constexpr int kHD = 64;
constexpr int kB  = 2;
constexpr int kL  = 1024;
constexpr int kTok = kB * kL;   // 2048

// ---------------- weight transpose+convert: fp32 [K][N] -> bf16-bits [N][K] ----------------
__global__ __launch_bounds__(256) void transpose_bf16(
    const float* __restrict__ src, short* __restrict__ dst, int K, int N)
{
    __shared__ float t[32][33];
    int n0 = blockIdx.x * 32, k0 = blockIdx.y * 32;
    int tx = threadIdx.x & 31, ty = threadIdx.x >> 5;  // ty 0..7
    #pragma unroll
    for (int r = ty; r < 32; r += 8)
        t[r][tx] = src[(size_t)(k0 + r) * N + n0 + tx];
    __syncthreads();
    #pragma unroll
    for (int r = ty; r < 32; r += 8) {
        hbf16 h = __float2bfloat16(t[tx][r]);
        dst[(size_t)(n0 + r) * K + k0 + tx] = *(short*)&h;
    }
}

// ---------------- MFMA GEMM: C[M,N] f32 = A[M,K] f32 @ WT[N,K] bf16 + bias f32, opt GELU ----------------
// 128x128 tile, BK=32, 4 waves each computing 64x64 via 4x4 grid of 16x16x32 MFMA.
// LDS rows padded to 40 shorts (80B, 16B-aligned; 2-way bank aliasing = free).
constexpr int LDK = 40;
__global__ __launch_bounds__(256) void gemm_mfma(
    const float* __restrict__ A, const short* __restrict__ WT,
    const float* __restrict__ bias, float* __restrict__ C,
    int M, int N, int K, int act)
{
    __shared__ short As[128 * LDK];
    __shared__ short Bs[128 * LDK];
    const int tid = threadIdx.x;
    const int m0 = blockIdx.y * 128, n0 = blockIdx.x * 128;
    const int wave = tid >> 6, lane = tid & 63;
    const int wm = (wave & 1) * 64, wn = (wave >> 1) * 64;
    const int l15 = lane & 15, quad = lane >> 4;

    f32x4 acc[4][4];
    #pragma unroll
    for (int i = 0; i < 4; ++i)
        #pragma unroll
        for (int j = 0; j < 4; ++j)
            acc[i][j] = (f32x4){0.f, 0.f, 0.f, 0.f};

    for (int kk = 0; kk < K; kk += 32) {
        // stage A: 128x32 fp32 -> bf16 LDS (coalesced float4 reads, short4 LDS writes)
        #pragma unroll
        for (int e = 0; e < 4; ++e) {
            int idx = tid + e * 256;            // 0..1023
            int m = idx >> 3, kq = (idx & 7) * 4;
            const float4 a4 = *(const float4*)&A[(size_t)(m0 + m) * K + kk + kq];
            hbf16 h0 = __float2bfloat16(a4.x), h1 = __float2bfloat16(a4.y);
            hbf16 h2 = __float2bfloat16(a4.z), h3 = __float2bfloat16(a4.w);
            short4 s4 = make_short4(*(short*)&h0, *(short*)&h1, *(short*)&h2, *(short*)&h3);
            *(short4*)&As[m * LDK + kq] = s4;
        }
        // stage B: 128x32 bf16 straight copy (16B chunks)
        #pragma unroll
        for (int e = 0; e < 2; ++e) {
            int idx = tid + e * 256;            // 0..511
            int n = idx >> 2, kg = (idx & 3) * 8;
            *(bf16x8*)&Bs[n * LDK + kg] = *(const bf16x8*)&WT[(size_t)(n0 + n) * K + kk + kg];
        }
        __syncthreads();

        bf16x8 af[4], bfr[4];
        #pragma unroll
        for (int i = 0; i < 4; ++i)
            af[i] = *(bf16x8*)&As[(wm + i * 16 + l15) * LDK + quad * 8];
        #pragma unroll
        for (int j = 0; j < 4; ++j)
            bfr[j] = *(bf16x8*)&Bs[(wn + j * 16 + l15) * LDK + quad * 8];
        #pragma unroll
        for (int i = 0; i < 4; ++i)
            #pragma unroll
            for (int j = 0; j < 4; ++j)
                acc[i][j] = __builtin_amdgcn_mfma_f32_16x16x32_bf16(af[i], bfr[j], acc[i][j], 0, 0, 0);
        __syncthreads();
    }

    // epilogue: bias (+GELU), fp32 stores. C/D map: col=lane&15, row=quad*4+reg.
    #pragma unroll
    for (int j = 0; j < 4; ++j) {
        int n = n0 + wn + j * 16 + l15;
        float bv = bias[n];
        #pragma unroll
        for (int i = 0; i < 4; ++i) {
            int mb = m0 + wm + i * 16 + quad * 4;
            #pragma unroll
            for (int r = 0; r < 4; ++r) {
                float v = acc[i][j][r] + bv;
                if (act) v = v * 0.5f * (1.0f + erff(v * 0.70710678118654752f));
                C[(size_t)(mb + r) * N + n] = v;
            }
        }
    }
}

// ---------------- RoPE in-place ----------------
__global__ void rope_kernel(float* __restrict__ x, const float* __restrict__ pos) {
    int idx = blockIdx.x * blockDim.x + threadIdx.x;
    if (idx >= kTok * kH * 32) return;
    int d = idx & 31;
    int h = (idx >> 5) & (kH - 1);
    int row = idx >> 9;
    int l = row & (kL - 1);
    float a1 = pos[l * kHD + d];
    float a2 = pos[l * kHD + d + 32];
    size_t base = (size_t)row * kD + h * kHD;
    float x1 = x[base + d], x2 = x[base + d + 32];
    x[base + d]      = x1 * cosf(a1) - x2 * sinf(a1);
    x[base + d + 32] = x2 * cosf(a2) + x1 * sinf(a2);
}

// ---------------- flash-style tiled attention (unchanged from R4) ----------------
constexpr int TQ = 64, TK = 64;
constexpr int LDP = 68;
__global__ __launch_bounds__(256) void attn_tile(
    const float* __restrict__ q, const float* __restrict__ k,
    const float* __restrict__ v, const float* __restrict__ alibi,
    const int* __restrict__ mask, float* __restrict__ out)
{
    const int q0 = blockIdx.x * TQ, h = blockIdx.y, b = blockIdx.z;
    const int tid = threadIdx.x;
    const int tx = tid & 15, ty = tid >> 4;
    __shared__ float QsT[kHD][LDP];
    __shared__ float KsT[kHD][LDP];
    __shared__ float Vs[TK][LDP];
    __shared__ float SsT[TK][LDP];
    __shared__ float mrow[TQ], lrow[TQ], arow[TQ];

    #pragma unroll
    for (int e = 0; e < 4; ++e) {
        int i = tid + e * 256;
        int r = i >> 4, c4 = (i & 15) * 4;
        const float4 qv = *(const float4*)&q[(size_t)(b * kL + q0 + r) * kD + h * kHD + c4];
        QsT[c4][r] = qv.x; QsT[c4 + 1][r] = qv.y; QsT[c4 + 2][r] = qv.z; QsT[c4 + 3][r] = qv.w;
    }
    if (tid < TQ) { mrow[tid] = -3e38f; lrow[tid] = 0.f; }
    float o[4][4] = {};
    __syncthreads();

    for (int k0 = 0; k0 < kL; k0 += TK) {
        #pragma unroll
        for (int e = 0; e < 4; ++e) {
            int i = tid + e * 256;
            int r = i >> 4, c4 = (i & 15) * 4;
            size_t g = (size_t)(b * kL + k0 + r) * kD + h * kHD + c4;
            const float4 kv = *(const float4*)&k[g];
            KsT[c4][r] = kv.x; KsT[c4 + 1][r] = kv.y; KsT[c4 + 2][r] = kv.z; KsT[c4 + 3][r] = kv.w;
            const float4 vv = *(const float4*)&v[g];
            Vs[r][c4] = vv.x; Vs[r][c4 + 1] = vv.y; Vs[r][c4 + 2] = vv.z; Vs[r][c4 + 3] = vv.w;
        }
        __syncthreads();

        float acc[4][4] = {};
        #pragma unroll 8
        for (int kd = 0; kd < kHD; ++kd) {
            float4 a4 = *(const float4*)&QsT[kd][ty * 4];
            float4 b4 = *(const float4*)&KsT[kd][tx * 4];
            const float av[4] = {a4.x, a4.y, a4.z, a4.w};
            const float bv[4] = {b4.x, b4.y, b4.z, b4.w};
            #pragma unroll
            for (int i = 0; i < 4; ++i)
                #pragma unroll
                for (int j = 0; j < 4; ++j)
                    acc[i][j] += av[i] * bv[j];
        }
        const int4 mk = *(const int4*)&mask[b * kL + k0 + tx * 4];
        const int mkv[4] = {mk.x, mk.y, mk.z, mk.w};
        #pragma unroll
        for (int i = 0; i < 4; ++i) {
            const float4 al = *(const float4*)&alibi[((size_t)h * kL + q0 + ty * 4 + i) * kL + k0 + tx * 4];
            const float alv[4] = {al.x, al.y, al.z, al.w};
            #pragma unroll
            for (int j = 0; j < 4; ++j) {
                float s = mkv[j] ? -1e30f : acc[i][j] * 0.125f;
                SsT[tx * 4 + j][ty * 4 + i] = s + alv[j];
            }
        }
        __syncthreads();

        if (tid < TQ) {
            float tm = -3e38f;
            #pragma unroll 8
            for (int kk = 0; kk < TK; ++kk) tm = fmaxf(tm, SsT[kk][tid]);
            float mo = mrow[tid];
            float mn = fmaxf(mo, tm);
            float al = __expf(mo - mn);
            float ls = 0.f;
            #pragma unroll 8
            for (int kk = 0; kk < TK; ++kk) {
                float p = __expf(SsT[kk][tid] - mn);
                SsT[kk][tid] = p;
                ls += p;
            }
            mrow[tid] = mn;
            lrow[tid] = lrow[tid] * al + ls;
            arow[tid] = al;
        }
        __syncthreads();

        float alf[4];
        #pragma unroll
        for (int i = 0; i < 4; ++i) alf[i] = arow[ty * 4 + i];
        #pragma unroll
        for (int i = 0; i < 4; ++i)
            #pragma unroll
            for (int j = 0; j < 4; ++j)
                o[i][j] *= alf[i];
        #pragma unroll 8
        for (int kk = 0; kk < TK; ++kk) {
            float4 p4 = *(const float4*)&SsT[kk][ty * 4];
            float4 v4 = *(const float4*)&Vs[kk][tx * 4];
            const float pv[4] = {p4.x, p4.y, p4.z, p4.w};
            const float vv[4] = {v4.x, v4.y, v4.z, v4.w};
            #pragma unroll
            for (int i = 0; i < 4; ++i)
                #pragma unroll
                for (int j = 0; j < 4; ++j)
                    o[i][j] += pv[i] * vv[j];
        }
        __syncthreads();
    }

    #pragma unroll
    for (int i = 0; i < 4; ++i) {
        float inv = 1.f / lrow[ty * 4 + i];
        float4 ov = make_float4(o[i][0] * inv, o[i][1] * inv, o[i][2] * inv, o[i][3] * inv);
        *(float4*)&out[(size_t)(b * kL + q0 + ty * 4 + i) * kD + h * kHD + tx * 4] = ov;
    }
}

// ---------------- out = res + LayerNorm(z) ----------------
__global__ __launch_bounds__(256) void add_ln(
    const float* __restrict__ res, const float* __restrict__ z,
    const float* __restrict__ g, const float* __restrict__ bi,
    float* __restrict__ out)
{
    int row = blockIdx.x, tid = threadIdx.x;
    __shared__ float red[256], red2[256];
    const float* zr = z + (size_t)row * kD;
    float s = 0.f, sq = 0.f;
    for (int i = tid; i < kD; i += 256) { float vv = zr[i]; s += vv; sq += vv * vv; }
    red[tid] = s; red2[tid] = sq; __syncthreads();
    for (int st = 128; st > 0; st >>= 1) {
        if (tid < st) { red[tid] += red[tid + st]; red2[tid] += red2[tid + st]; }
        __syncthreads();
    }
    float mean = red[0] / kD;
    float var = red2[0] / kD - mean * mean;
    float rstd = rsqrtf(var + 1e-5f);
    for (int i = tid; i < kD; i += 256) {
        float vv = (zr[i] - mean) * rstd * g[i] + bi[i];
        out[(size_t)row * kD + i] = res[(size_t)row * kD + i] + vv;
    }
}

// ---------------- out = LayerNorm(res + f) ----------------
__global__ __launch_bounds__(256) void ln_final(
    const float* __restrict__ res, const float* __restrict__ f,
    const float* __restrict__ g, const float* __restrict__ bi,
    float* __restrict__ out)
{
    int row = blockIdx.x, tid = threadIdx.x;
    __shared__ float tt[kD];
    __shared__ float red[256], red2[256];
    float s = 0.f, sq = 0.f;
    for (int i = tid; i < kD; i += 256) {
        float vv = res[(size_t)row * kD + i] + f[(size_t)row * kD + i];
        tt[i] = vv; s += vv; sq += vv * vv;
    }
    red[tid] = s; red2[tid] = sq; __syncthreads();
    for (int st = 128; st > 0; st >>= 1) {
        if (tid < st) { red[tid] += red[tid + st]; red2[tid] += red2[tid + st]; }
        __syncthreads();
    }
    float mean = red[0] / kD;
    float var = red2[0] / kD - mean * mean;
    float rstd = rsqrtf(var + 1e-5f);
    for (int i = tid; i < kD; i += 256)
        out[(size_t)row * kD + i] = (tt[i] - mean) * rstd * g[i] + bi[i];
}

extern "C" void kernel_launch(void* const* d_in, const int* in_sizes, int n_in,
                              void* d_out, int out_size, void* d_ws, size_t ws_size,
                              hipStream_t stream)
{
    const float* memory      = (const float*)d_in[0];
    const float* tgt         = (const float*)d_in[1];
    const float* self_alibi  = (const float*)d_in[2];
    const float* self_pos    = (const float*)d_in[3];
    const float* cross_alibi = (const float*)d_in[4];
    const float* cross_pos   = (const float*)d_in[5];
    const int*   mask        = (const int*)d_in[6];
    const float* sa_lat_w = (const float*)d_in[7];   const float* sa_lat_b = (const float*)d_in[8];
    const float* sa_q_w   = (const float*)d_in[9];   const float* sa_q_b   = (const float*)d_in[10];
    const float* sa_k_w   = (const float*)d_in[11];  const float* sa_k_b   = (const float*)d_in[12];
    const float* sa_v_w   = (const float*)d_in[13];  const float* sa_v_b   = (const float*)d_in[14];
    const float* sa_out_w = (const float*)d_in[15];  const float* sa_out_b = (const float*)d_in[16];
    const float* ca_lat_w = (const float*)d_in[17];  const float* ca_lat_b = (const float*)d_in[18];
    const float* ca_q_w   = (const float*)d_in[19];  const float* ca_q_b   = (const float*)d_in[20];
    const float* ca_k_w   = (const float*)d_in[21];  const float* ca_k_b   = (const float*)d_in[22];
    const float* ca_v_w   = (const float*)d_in[23];  const float* ca_v_b   = (const float*)d_in[24];
    const float* ca_out_w = (const float*)d_in[25];  const float* ca_out_b = (const float*)d_in[26];
    const float* lin1_w   = (const float*)d_in[27];  const float* lin1_b   = (const float*)d_in[28];
    const float* lin2_w   = (const float*)d_in[29];  const float* lin2_b   = (const float*)d_in[30];
    const float* n1_g = (const float*)d_in[31];  const float* n1_b = (const float*)d_in[32];
    const float* n2_g = (const float*)d_in[33];  const float* n2_b = (const float*)d_in[34];
    const float* n3_g = (const float*)d_in[35];  const float* n3_b = (const float*)d_in[36];

    // workspace: 13M floats (52MB) activations + 4M shorts (8MB) rotating weight slot = 60MB
    const size_t M1 = 1u << 20;
    float* W    = (float*)d_ws;
    float* xb   = W + 0 * M1;    // 2M — residual stream
    float* tmp  = W + 2 * M1;    // 2M — pre-LN tensor
    float* proj = W + 4 * M1;    // 1M — latent projection
    float* qb   = W + 5 * M1;    // 2M
    float* kb   = W + 7 * M1;    // 2M
    float* vb   = W + 9 * M1;    // 2M
    float* attn = W + 11 * M1;   // 2M
    float* ffh  = W + 4 * M1;    // 8M — overlays proj/q/k/v/attn during FFN
    short* wslot = (short*)(W + 13 * M1);  // 4M shorts

    auto gemm = [&](const float* A, const float* Wt, const float* bias, float* C,
                    int M, int N, int K, int act) {
        transpose_bf16<<<dim3(N / 32, K / 32), dim3(256), 0, stream>>>(Wt, wslot, K, N);
        gemm_mfma<<<dim3(N / 128, M / 128), dim3(256), 0, stream>>>(A, wslot, bias, C, M, N, K, act);
    };
    dim3 agrid(kL / TQ, kH, kB);

    // ---- self attention ----
    gemm(tgt, sa_lat_w, sa_lat_b, proj, kTok, kP, kD, 0);
    gemm(proj, sa_q_w, sa_q_b, qb, kTok, kD, kP, 0);
    gemm(proj, sa_k_w, sa_k_b, kb, kTok, kD, kP, 0);
    gemm(proj, sa_v_w, sa_v_b, vb, kTok, kD, kP, 0);
    rope_kernel<<<dim3(4096), dim3(256), 0, stream>>>(qb, self_pos);
    rope_kernel<<<dim3(4096), dim3(256), 0, stream>>>(kb, self_pos);
    attn_tile<<<agrid, dim3(256), 0, stream>>>(qb, kb, vb, self_alibi, mask, attn);
    gemm(attn, sa_out_w, sa_out_b, tmp, kTok, kD, kD, 0);
    add_ln<<<dim3(kTok), dim3(256), 0, stream>>>(tgt, tmp, n1_g, n1_b, xb);

    // ---- cross attention ----
    gemm(memory, ca_lat_w, ca_lat_b, proj, kTok, kP, kD, 0);
    gemm(xb, ca_q_w, ca_q_b, qb, kTok, kD, kD, 0);
    gemm(proj, ca_k_w, ca_k_b, kb, kTok, kD, kP, 0);
    gemm(proj, ca_v_w, ca_v_b, vb, kTok, kD, kP, 0);
    rope_kernel<<<dim3(4096), dim3(256), 0, stream>>>(qb, cross_pos);
    rope_kernel<<<dim3(4096), dim3(256), 0, stream>>>(kb, cross_pos);
    attn_tile<<<agrid, dim3(256), 0, stream>>>(qb, kb, vb, cross_alibi, mask, attn);
    gemm(attn, ca_out_w, ca_out_b, tmp, kTok, kD, kD, 0);
    add_ln<<<dim3(kTok), dim3(256), 0, stream>>>(xb, tmp, n2_g, n2_b, xb);

    // ---- FFN ----
    gemm(xb, lin1_w, lin1_b, ffh, kTok, kFF, kD, 1);
    gemm(ffh, lin2_w, lin2_b, tmp, kTok, kD, kFF, 0);
    ln_final<<<dim3(kTok), dim3(256), 0, stream>>>(xb, tmp, n3_g, n3_b, (float*)d_out);
}

// Round 6
// 868.009 us; speedup vs baseline: 7.2728x; 1.3262x over previous
//
#include <hip/hip_runtime.h>
#include <hip/hip_bf16.h>
#include <math.h>

typedef __hip_bfloat16 hbf16;
typedef __attribute__((ext_vector_type(8))) short bf16x8;
typedef __attribute__((ext_vector_type(4))) float f32x4;

constexpr int kD  = 1024;
constexpr int kP  = 512;
constexpr int kH  = 16;
constexpr int kFF = 4096;
constexpr int kHD = 64;
constexpr int kB  = 2;
constexpr int kL  = 1024;
constexpr int kTok = kB * kL;   // 2048

__device__ inline short f2bf(float x) { hbf16 h = __float2bfloat16(x); return *(short*)&h; }

// ---------------- weight transpose+convert: fp32 [K][N] -> bf16-bits [N][K] ----------------
__global__ __launch_bounds__(256) void transpose_bf16(
    const float* __restrict__ src, short* __restrict__ dst, int K, int N)
{
    __shared__ float t[32][33];
    int n0 = blockIdx.x * 32, k0 = blockIdx.y * 32;
    int tx = threadIdx.x & 31, ty = threadIdx.x >> 5;
    #pragma unroll
    for (int r = ty; r < 32; r += 8)
        t[r][tx] = src[(size_t)(k0 + r) * N + n0 + tx];
    __syncthreads();
    #pragma unroll
    for (int r = ty; r < 32; r += 8)
        dst[(size_t)(n0 + r) * K + k0 + tx] = f2bf(t[tx][r]);
}

// ---------------- MFMA GEMM (unchanged from R5) ----------------
constexpr int LDK = 40;
__global__ __launch_bounds__(256) void gemm_mfma(
    const float* __restrict__ A, const short* __restrict__ WT,
    const float* __restrict__ bias, float* __restrict__ C,
    int M, int N, int K, int act)
{
    __shared__ short As[128 * LDK];
    __shared__ short Bs[128 * LDK];
    const int tid = threadIdx.x;
    const int m0 = blockIdx.y * 128, n0 = blockIdx.x * 128;
    const int wave = tid >> 6, lane = tid & 63;
    const int wm = (wave & 1) * 64, wn = (wave >> 1) * 64;
    const int l15 = lane & 15, quad = lane >> 4;

    f32x4 acc[4][4];
    #pragma unroll
    for (int i = 0; i < 4; ++i)
        #pragma unroll
        for (int j = 0; j < 4; ++j)
            acc[i][j] = (f32x4){0.f, 0.f, 0.f, 0.f};

    for (int kk = 0; kk < K; kk += 32) {
        #pragma unroll
        for (int e = 0; e < 4; ++e) {
            int idx = tid + e * 256;
            int m = idx >> 3, kq = (idx & 7) * 4;
            const float4 a4 = *(const float4*)&A[(size_t)(m0 + m) * K + kk + kq];
            short4 s4 = make_short4(f2bf(a4.x), f2bf(a4.y), f2bf(a4.z), f2bf(a4.w));
            *(short4*)&As[m * LDK + kq] = s4;
        }
        #pragma unroll
        for (int e = 0; e < 2; ++e) {
            int idx = tid + e * 256;
            int n = idx >> 2, kg = (idx & 3) * 8;
            *(bf16x8*)&Bs[n * LDK + kg] = *(const bf16x8*)&WT[(size_t)(n0 + n) * K + kk + kg];
        }
        __syncthreads();

        bf16x8 af[4], bfr[4];
        #pragma unroll
        for (int i = 0; i < 4; ++i)
            af[i] = *(bf16x8*)&As[(wm + i * 16 + l15) * LDK + quad * 8];
        #pragma unroll
        for (int j = 0; j < 4; ++j)
            bfr[j] = *(bf16x8*)&Bs[(wn + j * 16 + l15) * LDK + quad * 8];
        #pragma unroll
        for (int i = 0; i < 4; ++i)
            #pragma unroll
            for (int j = 0; j < 4; ++j)
                acc[i][j] = __builtin_amdgcn_mfma_f32_16x16x32_bf16(af[i], bfr[j], acc[i][j], 0, 0, 0);
        __syncthreads();
    }

    #pragma unroll
    for (int j = 0; j < 4; ++j) {
        int n = n0 + wn + j * 16 + l15;
        float bv = bias[n];
        #pragma unroll
        for (int i = 0; i < 4; ++i) {
            int mb = m0 + wm + i * 16 + quad * 4;
            #pragma unroll
            for (int r = 0; r < 4; ++r) {
                float v = acc[i][j][r] + bv;
                if (act) v = v * 0.5f * (1.0f + erff(v * 0.70710678118654752f));
                C[(size_t)(mb + r) * N + n] = v;
            }
        }
    }
}

// ---------------- qk_pack: RoPE + optional scale + bf16 cast, [Tok,D] -> [b,h,l,64] ----------------
__global__ void qk_pack(const float* __restrict__ x, const float* __restrict__ pos,
                        short* __restrict__ outp, float scale)
{
    int idx = blockIdx.x * blockDim.x + threadIdx.x;
    if (idx >= kTok * kH * 32) return;
    int d = idx & 31;
    int h = (idx >> 5) & (kH - 1);
    int row = idx >> 9;
    int l = row & (kL - 1);
    int b = row >> 10;
    float a1 = pos[l * kHD + d];
    float a2 = pos[l * kHD + d + 32];
    size_t base = (size_t)row * kD + h * kHD;
    float x1 = x[base + d], x2 = x[base + d + 32];
    float r1 = (x1 * cosf(a1) - x2 * sinf(a1)) * scale;
    float r2 = (x2 * cosf(a2) + x1 * sinf(a2)) * scale;
    size_t ob = ((size_t)(b * kH + h) * kL + l) * 64;
    outp[ob + d]      = f2bf(r1);
    outp[ob + d + 32] = f2bf(r2);
}

// ---------------- v_pack: transpose [Tok,D] fp32 -> [b,h,hd,l] bf16 ----------------
__global__ __launch_bounds__(256) void v_pack(const float* __restrict__ v, short* __restrict__ outp)
{
    int l0 = blockIdx.x * 64, h = blockIdx.y, b = blockIdx.z;
    __shared__ float t[64][65];
    int tid = threadIdx.x;
    #pragma unroll
    for (int e = 0; e < 4; ++e) {
        int idx = tid + e * 256;
        int r = idx >> 4, c4 = (idx & 15) * 4;
        const float4 vv = *(const float4*)&v[(size_t)(b * kL + l0 + r) * kD + h * kHD + c4];
        t[r][c4] = vv.x; t[r][c4 + 1] = vv.y; t[r][c4 + 2] = vv.z; t[r][c4 + 3] = vv.w;
    }
    __syncthreads();
    int hd = tid >> 2, seg = (tid & 3) * 16;
    size_t ob = ((size_t)(b * kH + h) * 64 + hd) * kL + l0 + seg;
    short tmp[16];
    #pragma unroll
    for (int i = 0; i < 16; ++i) tmp[i] = f2bf(t[seg + i][hd]);
    #pragma unroll
    for (int i = 0; i < 16; i += 4)
        *(short4*)&outp[ob + i] = make_short4(tmp[i], tmp[i + 1], tmp[i + 2], tmp[i + 3]);
}

// ---------------- MFMA flash attention ----------------
// block = (b, h, 64 q-rows); 4 waves x 16 q-rows; TK=64 key tiles; online softmax in registers.
constexpr int AQ = 64, AK = 64;
constexpr int QLD = 72;   // shorts/row = 144 B (16B-aligned)
constexpr int PLD = 68;   // floats/row for P
__global__ __launch_bounds__(256) void attn_mfma(
    const short* __restrict__ qpk, const short* __restrict__ kpk,
    const short* __restrict__ vpk, const float* __restrict__ alibi,
    const int* __restrict__ mask, float* __restrict__ out)
{
    const int q0 = blockIdx.x * AQ, h = blockIdx.y, b = blockIdx.z;
    const int tid = threadIdx.x, wave = tid >> 6, lane = tid & 63;
    const int l15 = lane & 15, quad = lane >> 4;
    __shared__ short Qs[AQ * QLD];
    __shared__ short Ks[AK * QLD];
    __shared__ short Vt[kHD * QLD];
    __shared__ float Ps[AQ * PLD];

    const short* qbase = qpk + ((size_t)(b * kH + h) * kL) * 64;
    const short* kbase = kpk + ((size_t)(b * kH + h) * kL) * 64;
    const short* vbase = vpk + ((size_t)(b * kH + h) * 64) * kL;

    // stage Q once (straight bf16 copy)
    #pragma unroll
    for (int e = 0; e < 2; ++e) {
        int idx = tid + e * 256;
        int r = idx >> 3, c8 = (idx & 7) * 8;
        *(bf16x8*)&Qs[r * QLD + c8] = *(const bf16x8*)&qbase[(size_t)(q0 + r) * 64 + c8];
    }
    float mst[4], lst[4];
    #pragma unroll
    for (int r = 0; r < 4; ++r) { mst[r] = -3e38f; lst[r] = 0.f; }
    f32x4 oacc[4];
    #pragma unroll
    for (int j = 0; j < 4; ++j) oacc[j] = (f32x4){0.f, 0.f, 0.f, 0.f};
    __syncthreads();

    for (int k0 = 0; k0 < kL; k0 += AK) {
        // ---- stage K [key][hd] and Vt [hd][key] (straight copies) ----
        #pragma unroll
        for (int e = 0; e < 2; ++e) {
            int idx = tid + e * 256;
            int r = idx >> 3, c8 = (idx & 7) * 8;
            *(bf16x8*)&Ks[r * QLD + c8] = *(const bf16x8*)&kbase[(size_t)(k0 + r) * 64 + c8];
            *(bf16x8*)&Vt[r * QLD + c8] = *(const bf16x8*)&vbase[(size_t)r * kL + k0 + c8];
        }
        __syncthreads();

        // ---- S = Q K^T : 4 n-tiles x 2 k-steps ----
        bf16x8 aq[2];
        #pragma unroll
        for (int s = 0; s < 2; ++s)
            aq[s] = *(bf16x8*)&Qs[(wave * 16 + l15) * QLD + s * 32 + quad * 8];
        f32x4 sacc[4];
        #pragma unroll
        for (int nt = 0; nt < 4; ++nt) sacc[nt] = (f32x4){0.f, 0.f, 0.f, 0.f};
        #pragma unroll
        for (int nt = 0; nt < 4; ++nt)
            #pragma unroll
            for (int s = 0; s < 2; ++s) {
                bf16x8 bk = *(bf16x8*)&Ks[(nt * 16 + l15) * QLD + s * 32 + quad * 8];
                sacc[nt] = __builtin_amdgcn_mfma_f32_16x16x32_bf16(aq[s], bk, sacc[nt], 0, 0, 0);
            }

        // ---- epilogue: mask -> -1e30, + alibi; online softmax (registers) ----
        float sv[4][4];
        float mx[4] = {-3e38f, -3e38f, -3e38f, -3e38f};
        #pragma unroll
        for (int nt = 0; nt < 4; ++nt) {
            int key = k0 + nt * 16 + l15;
            int mk = mask[b * kL + key];
            #pragma unroll
            for (int r = 0; r < 4; ++r) {
                int qrow = q0 + wave * 16 + quad * 4 + r;
                float al = alibi[((size_t)h * kL + qrow) * kL + key];
                float s = mk ? -1e30f : sacc[nt][r];
                s += al;
                sv[nt][r] = s;
                mx[r] = fmaxf(mx[r], s);
            }
        }
        #pragma unroll
        for (int m = 1; m <= 8; m <<= 1)
            #pragma unroll
            for (int r = 0; r < 4; ++r)
                mx[r] = fmaxf(mx[r], __shfl_xor(mx[r], m));
        float alpha[4], lsum[4];
        #pragma unroll
        for (int r = 0; r < 4; ++r) {
            float mn = fmaxf(mst[r], mx[r]);
            alpha[r] = __expf(mst[r] - mn);
            mst[r] = mn;
            lsum[r] = 0.f;
        }
        #pragma unroll
        for (int nt = 0; nt < 4; ++nt)
            #pragma unroll
            for (int r = 0; r < 4; ++r) {
                float p = __expf(sv[nt][r] - mst[r]);
                sv[nt][r] = p;
                lsum[r] += p;
            }
        #pragma unroll
        for (int m = 1; m <= 8; m <<= 1)
            #pragma unroll
            for (int r = 0; r < 4; ++r)
                lsum[r] += __shfl_xor(lsum[r], m);
        #pragma unroll
        for (int r = 0; r < 4; ++r) lst[r] = lst[r] * alpha[r] + lsum[r];

        // write P (fp32) to LDS [q][key]; rescale O
        #pragma unroll
        for (int nt = 0; nt < 4; ++nt)
            #pragma unroll
            for (int r = 0; r < 4; ++r)
                Ps[(wave * 16 + quad * 4 + r) * PLD + nt * 16 + l15] = sv[nt][r];
        #pragma unroll
        for (int j = 0; j < 4; ++j)
            #pragma unroll
            for (int r = 0; r < 4; ++r)
                oacc[j][r] *= alpha[r];
        __syncthreads();

        // ---- O += P V : A-frag from Ps (cvt to bf16), B-frag from Vt ----
        #pragma unroll
        for (int s = 0; s < 2; ++s) {
            const float* pr = &Ps[(wave * 16 + l15) * PLD + s * 32 + quad * 8];
            float4 p0 = *(const float4*)&pr[0];
            float4 p1 = *(const float4*)&pr[4];
            bf16x8 ap;
            ap[0] = f2bf(p0.x); ap[1] = f2bf(p0.y); ap[2] = f2bf(p0.z); ap[3] = f2bf(p0.w);
            ap[4] = f2bf(p1.x); ap[5] = f2bf(p1.y); ap[6] = f2bf(p1.z); ap[7] = f2bf(p1.w);
            #pragma unroll
            for (int j = 0; j < 4; ++j) {
                bf16x8 bv = *(bf16x8*)&Vt[(j * 16 + l15) * QLD + s * 32 + quad * 8];
                oacc[j] = __builtin_amdgcn_mfma_f32_16x16x32_bf16(ap, bv, oacc[j], 0, 0, 0);
            }
        }
        __syncthreads();
    }

    // ---- epilogue: divide by l, write fp32 ----
    #pragma unroll
    for (int j = 0; j < 4; ++j)
        #pragma unroll
        for (int r = 0; r < 4; ++r) {
            int qrow = q0 + wave * 16 + quad * 4 + r;
            out[(size_t)(b * kL + qrow) * kD + h * kHD + j * 16 + l15] = oacc[j][r] / lst[r];
        }
}

// ---------------- out = res + LayerNorm(z) ----------------
__global__ __launch_bounds__(256) void add_ln(
    const float* __restrict__ res, const float* __restrict__ z,
    const float* __restrict__ g, const float* __restrict__ bi,
    float* __restrict__ out)
{
    int row = blockIdx.x, tid = threadIdx.x;
    __shared__ float red[256], red2[256];
    const float* zr = z + (size_t)row * kD;
    float s = 0.f, sq = 0.f;
    for (int i = tid; i < kD; i += 256) { float vv = zr[i]; s += vv; sq += vv * vv; }
    red[tid] = s; red2[tid] = sq; __syncthreads();
    for (int st = 128; st > 0; st >>= 1) {
        if (tid < st) { red[tid] += red[tid + st]; red2[tid] += red2[tid + st]; }
        __syncthreads();
    }
    float mean = red[0] / kD;
    float var = red2[0] / kD - mean * mean;
    float rstd = rsqrtf(var + 1e-5f);
    for (int i = tid; i < kD; i += 256) {
        float vv = (zr[i] - mean) * rstd * g[i] + bi[i];
        out[(size_t)row * kD + i] = res[(size_t)row * kD + i] + vv;
    }
}

// ---------------- out = LayerNorm(res + f) ----------------
__global__ __launch_bounds__(256) void ln_final(
    const float* __restrict__ res, const float* __restrict__ f,
    const float* __restrict__ g, const float* __restrict__ bi,
    float* __restrict__ out)
{
    int row = blockIdx.x, tid = threadIdx.x;
    __shared__ float tt[kD];
    __shared__ float red[256], red2[256];
    float s = 0.f, sq = 0.f;
    for (int i = tid; i < kD; i += 256) {
        float vv = res[(size_t)row * kD + i] + f[(size_t)row * kD + i];
        tt[i] = vv; s += vv; sq += vv * vv;
    }
    red[tid] = s; red2[tid] = sq; __syncthreads();
    for (int st = 128; st > 0; st >>= 1) {
        if (tid < st) { red[tid] += red[tid + st]; red2[tid] += red2[tid + st]; }
        __syncthreads();
    }
    float mean = red[0] / kD;
    float var = red2[0] / kD - mean * mean;
    float rstd = rsqrtf(var + 1e-5f);
    for (int i = tid; i < kD; i += 256)
        out[(size_t)row * kD + i] = (tt[i] - mean) * rstd * g[i] + bi[i];
}

extern "C" void kernel_launch(void* const* d_in, const int* in_sizes, int n_in,
                              void* d_out, int out_size, void* d_ws, size_t ws_size,
                              hipStream_t stream)
{
    const float* memory      = (const float*)d_in[0];
    const float* tgt         = (const float*)d_in[1];
    const float* self_alibi  = (const float*)d_in[2];
    const float* self_pos    = (const float*)d_in[3];
    const float* cross_alibi = (const float*)d_in[4];
    const float* cross_pos   = (const float*)d_in[5];
    const int*   mask        = (const int*)d_in[6];
    const float* sa_lat_w = (const float*)d_in[7];   const float* sa_lat_b = (const float*)d_in[8];
    const float* sa_q_w   = (const float*)d_in[9];   const float* sa_q_b   = (const float*)d_in[10];
    const float* sa_k_w   = (const float*)d_in[11];  const float* sa_k_b   = (const float*)d_in[12];
    const float* sa_v_w   = (const float*)d_in[13];  const float* sa_v_b   = (const float*)d_in[14];
    const float* sa_out_w = (const float*)d_in[15];  const float* sa_out_b = (const float*)d_in[16];
    const float* ca_lat_w = (const float*)d_in[17];  const float* ca_lat_b = (const float*)d_in[18];
    const float* ca_q_w   = (const float*)d_in[19];  const float* ca_q_b   = (const float*)d_in[20];
    const float* ca_k_w   = (const float*)d_in[21];  const float* ca_k_b   = (const float*)d_in[22];
    const float* ca_v_w   = (const float*)d_in[23];  const float* ca_v_b   = (const float*)d_in[24];
    const float* ca_out_w = (const float*)d_in[25];  const float* ca_out_b = (const float*)d_in[26];
    const float* lin1_w   = (const float*)d_in[27];  const float* lin1_b   = (const float*)d_in[28];
    const float* lin2_w   = (const float*)d_in[29];  const float* lin2_b   = (const float*)d_in[30];
    const float* n1_g = (const float*)d_in[31];  const float* n1_b = (const float*)d_in[32];
    const float* n2_g = (const float*)d_in[33];  const float* n2_b = (const float*)d_in[34];
    const float* n3_g = (const float*)d_in[35];  const float* n3_b = (const float*)d_in[36];

    // workspace: 15M floats = 60 MB
    const size_t M1 = 1u << 20;
    float* W     = (float*)d_ws;
    float* xb    = W + 0 * M1;    // 2M — residual stream
    float* tmp   = W + 2 * M1;    // 2M — pre-LN tensor (free during attention)
    float* proj  = W + 4 * M1;    // 1M — latent projection
    float* qb    = W + 5 * M1;    // 2M
    float* kb    = W + 7 * M1;    // 2M
    float* vb    = W + 9 * M1;    // 2M
    float* attnb = W + 11 * M1;   // 2M
    float* ffh   = W + 4 * M1;    // 8M — FFN hidden, overlays proj/qb/kb/vb
    short* wslot = (short*)(W + 13 * M1);  // 4M shorts
    // packed bf16 buffers overlay dead fp32 regions during the attention phase:
    short* qpk = (short*)(W + 2 * M1);   // 2M bf16 over tmp[0:1M]
    short* kpk = (short*)(W + 3 * M1);   // 2M bf16 over tmp[1M:2M]
    short* vpk = (short*)(W + 4 * M1);   // 2M bf16 over proj (dead after v-gemm)

    auto gemm = [&](const float* A, const float* Wt, const float* bias, float* C,
                    int M, int N, int K, int act) {
        transpose_bf16<<<dim3(N / 32, K / 32), dim3(256), 0, stream>>>(Wt, wslot, K, N);
        gemm_mfma<<<dim3(N / 128, M / 128), dim3(256), 0, stream>>>(A, wslot, bias, C, M, N, K, act);
    };
    dim3 agrid(kL / AQ, kH, kB);
    dim3 vgrid(kL / 64, kH, kB);

    // ---- self attention ----
    gemm(tgt, sa_lat_w, sa_lat_b, proj, kTok, kP, kD, 0);
    gemm(proj, sa_q_w, sa_q_b, qb, kTok, kD, kP, 0);
    gemm(proj, sa_k_w, sa_k_b, kb, kTok, kD, kP, 0);
    gemm(proj, sa_v_w, sa_v_b, vb, kTok, kD, kP, 0);
    qk_pack<<<dim3(4096), dim3(256), 0, stream>>>(qb, self_pos, qpk, 0.125f);
    qk_pack<<<dim3(4096), dim3(256), 0, stream>>>(kb, self_pos, kpk, 1.0f);
    v_pack<<<vgrid, dim3(256), 0, stream>>>(vb, vpk);
    attn_mfma<<<agrid, dim3(256), 0, stream>>>(qpk, kpk, vpk, self_alibi, mask, attnb);
    gemm(attnb, sa_out_w, sa_out_b, tmp, kTok, kD, kD, 0);
    add_ln<<<dim3(kTok), dim3(256), 0, stream>>>(tgt, tmp, n1_g, n1_b, xb);

    // ---- cross attention ----
    gemm(memory, ca_lat_w, ca_lat_b, proj, kTok, kP, kD, 0);
    gemm(xb, ca_q_w, ca_q_b, qb, kTok, kD, kD, 0);
    gemm(proj, ca_k_w, ca_k_b, kb, kTok, kD, kP, 0);
    gemm(proj, ca_v_w, ca_v_b, vb, kTok, kD, kP, 0);
    qk_pack<<<dim3(4096), dim3(256), 0, stream>>>(qb, cross_pos, qpk, 0.125f);
    qk_pack<<<dim3(4096), dim3(256), 0, stream>>>(kb, cross_pos, kpk, 1.0f);
    v_pack<<<vgrid, dim3(256), 0, stream>>>(vb, vpk);
    attn_mfma<<<agrid, dim3(256), 0, stream>>>(qpk, kpk, vpk, cross_alibi, mask, attnb);
    gemm(attnb, ca_out_w, ca_out_b, tmp, kTok, kD, kD, 0);
    add_ln<<<dim3(kTok), dim3(256), 0, stream>>>(xb, tmp, n2_g, n2_b, xb);

    // ---- FFN ----
    gemm(xb, lin1_w, lin1_b, ffh, kTok, kFF, kD, 1);
    gemm(ffh, lin2_w, lin2_b, tmp, kTok, kD, kFF, 0);
    ln_final<<<dim3(kTok), dim3(256), 0, stream>>>(xb, tmp, n3_g, n3_b, (float*)d_out);
}